// Round 7
// baseline (470.641 us; speedup 1.0000x reference)
//
#include <hip/hip_runtime.h>
#include <hip/hip_fp16.h>

#define NU 50000
#define NM 50000
#define NN 100000
#define FU 32
#define FM 64
#define HD 128
#define NC 10

#define NB 196      // buckets of 256 destination cols
#define CAP 8192    // per-bucket staging capacity
#define CHUNK 1024  // edges per k_bucket block (977 blocks -> good occupancy)

typedef __attribute__((ext_vector_type(8))) _Float16 half8;
typedef __attribute__((ext_vector_type(4))) float f32x4;

// ============ scan helpers ============

__device__ inline int wave_incl_scan(int x, int l) {
#pragma unroll
    for (int d = 1; d < 64; d <<= 1) {
        int u = __shfl_up(x, d, 64);
        if (l >= d) x += u;
    }
    return x;
}

template <int NWAVE>
__device__ inline int block_excl_scan(int v, int t, int* wsum, int* out_total) {
    int l = t & 63, w = t >> 6;
    int inc = wave_incl_scan(v, l);
    if (l == 63) wsum[w] = inc;
    __syncthreads();
    int base = 0;
    int tot = 0;
#pragma unroll
    for (int i = 0; i < NWAVE; i++) {
        int s = wsum[i];
        if (i < w) base += s;
        tot += s;
    }
    if (out_total) *out_total = tot;
    return base + inc - v;
}

// ============ bucketed CSR build ============
// pairs[b*CAP + i] = row | (col<<16), grouped by bucket b = col>>8

__global__ void k_bucket(const int* __restrict__ row, const int* __restrict__ col, int E,
                         int* __restrict__ bucket_cur, unsigned int* __restrict__ pairs) {
    __shared__ int hist[NB];
    __shared__ int lofs[NB];
    __shared__ int gbase[NB];
    __shared__ int lcur[NB];
    __shared__ int wsum[4];
    __shared__ unsigned int stage[CHUNK];
    int t = threadIdx.x;
    int e0 = blockIdx.x * CHUNK;
    int cnt = min(CHUNK, E - e0);
    for (int i = t; i < NB; i += 256) hist[i] = 0;
    __syncthreads();
    unsigned int pk[CHUNK / 256];
#pragma unroll
    for (int i = 0; i < CHUNK / 256; i++) {
        int k = i * 256 + t;
        if (k < cnt) {
            unsigned int r = (unsigned int)row[e0 + k];
            unsigned int c = (unsigned int)col[e0 + k];
            pk[i] = r | (c << 16);
            atomicAdd(&hist[c >> 8], 1);
        }
    }
    __syncthreads();
    int v = (t < NB) ? hist[t] : 0;
    int excl = block_excl_scan<4>(v, t, wsum, nullptr);
    if (t < NB) {
        lofs[t] = excl;
        lcur[t] = excl;
        gbase[t] = atomicAdd(&bucket_cur[t], v);
    }
    __syncthreads();
#pragma unroll
    for (int i = 0; i < CHUNK / 256; i++) {
        int k = i * 256 + t;
        if (k < cnt) {
            int pos = atomicAdd(&lcur[pk[i] >> 24], 1);  // (c>>8) == pk>>24
            stage[pos] = pk[i];
        }
    }
    __syncthreads();
    int w = t >> 6, l = t & 63;
    for (int b = w; b < NB; b += 4) {
        int start = lofs[b], n = hist[b];
        unsigned int g = (unsigned int)b * CAP + (unsigned int)gbase[b];
        for (int i = l; i < n; i += 64) pairs[g + i] = stage[start + i];
    }
}

// per-col degree counts from bucketed pairs (one block per bucket)
__global__ void k_bcount(const unsigned int* __restrict__ pairs,
                         const int* __restrict__ bucket_cur, int* __restrict__ counts) {
    __shared__ int lc[256];
    int b = blockIdx.x, t = threadIdx.x;
    lc[t] = 0;
    __syncthreads();
    int n = bucket_cur[b];
    unsigned int base = (unsigned int)b * CAP;
    for (int i = t; i < n; i += 256) {
        unsigned int c = pairs[base + i] >> 16;
        atomicAdd(&lc[c & 255], 1);
    }
    __syncthreads();
    int col0 = b << 8;
    if (col0 + t < NU) counts[col0 + t] = lc[t];
}

__global__ void k_scanA(const int* __restrict__ counts, int* __restrict__ sums) {
    __shared__ int wsum[4];
    int t = threadIdx.x;
    int idx = blockIdx.x * 256 + t;
    int v = (idx < NU) ? counts[idx] : 0;
    int total;
    block_excl_scan<4>(v, t, wsum, &total);
    if (t == 0) sums[blockIdx.x] = total;
}

__global__ void k_scanB(int* __restrict__ sums, int nblk, int* __restrict__ offsets) {
    __shared__ int wsum[4];
    int t = threadIdx.x;  // 256
    int v = (t < nblk) ? sums[t] : 0;
    int total;
    int excl = block_excl_scan<4>(v, t, wsum, &total);
    if (t < nblk) sums[t] = excl;
    if (t == 0) offsets[NU] = total;
}

__global__ void k_scanC(const int* __restrict__ counts, const int* __restrict__ sums,
                        int* __restrict__ offsets, float* __restrict__ dinv) {
    __shared__ int wsum[4];
    int t = threadIdx.x;
    int idx = blockIdx.x * 256 + t;
    int v = (idx < NU) ? counts[idx] : 0;
    int excl = block_excl_scan<4>(v, t, wsum, nullptr);
    if (idx < NU) {
        offsets[idx] = sums[blockIdx.x] + excl;
        dinv[idx] = rsqrtf((float)(v + 1));
    }
}

// scatter within bucket window (one block per bucket); csr stored as u16
__global__ void k_scatter(const unsigned int* __restrict__ pairs,
                          const int* __restrict__ bucket_cur, const int* __restrict__ offsets,
                          unsigned short* __restrict__ csr16) {
    __shared__ int lcur[256];
    int b = blockIdx.x, t = threadIdx.x;
    int col0 = b << 8;
    lcur[t] = (col0 + t < NU) ? offsets[col0 + t] : 0;
    __syncthreads();
    int n = bucket_cur[b];
    unsigned int base = (unsigned int)b * CAP;
    for (int i = t; i < n; i += 256) {
        unsigned int pk = pairs[base + i];
        int pos = atomicAdd(&lcur[(pk >> 16) & 255], 1);
        csr16[pos] = (unsigned short)(pk & 0xffffu);
    }
}

// ============ weight folding ============

__global__ void k_fold(const float* __restrict__ Wu, const float* __restrict__ bu,
                       const float* __restrict__ Wm, const float* __restrict__ bm,
                       const float* __restrict__ W1, const float* __restrict__ b1,
                       const float* __restrict__ W2,
                       float* __restrict__ WcUT, float* __restrict__ bcU,
                       float* __restrict__ WcMT, float* __restrict__ bcM,
                       float* __restrict__ W2T) {
    int bid = blockIdx.x, t = threadIdx.x;
    if (bid < 16) {                       // WcUT[k][c], k<32, c<128
        int f = bid * 256 + t;
        int k = f >> 7, c = f & 127;
        float s = 0.f;
        for (int j = 0; j < 128; j++) s += W1[c * 128 + j] * Wu[j * 32 + k];
        WcUT[f] = s;
    } else if (bid < 48) {                // WcMT[k][c], k<64
        int f = (bid - 16) * 256 + t;
        int k = f >> 7, c = f & 127;
        float s = 0.f;
        for (int j = 0; j < 128; j++) s += W1[c * 128 + j] * Wm[j * 64 + k];
        WcMT[f] = s;
    } else if (bid < 112) {               // W2T[k][c] = W2[c][k]
        int f = (bid - 48) * 256 + t;
        int k = f >> 7, c = f & 127;
        W2T[f] = W2[c * 128 + k];
    } else {
        if (t < 128) {
            float s = 0.f;
            for (int j = 0; j < 128; j++) s += W1[t * 128 + j] * bu[j];
            bcU[t] = s + b1[t];
        } else if (t < 256) {
            int c = t - 128;
            float s = 0.f;
            for (int j = 0; j < 128; j++) s += W1[c * 128 + j] * bm[j];
            bcM[c] = s + b1[c];
        }
    }
}

// ============ MFMA B-fragment tables (fp16, lane-ordered) ============
__global__ void k_wfrag(const float* __restrict__ WcUT, const float* __restrict__ WcMT,
                        const float* __restrict__ W2T,
                        _Float16* __restrict__ fragWcU, _Float16* __restrict__ fragWcM,
                        _Float16* __restrict__ fragW2) {
    int g = blockIdx.x * 256 + threadIdx.x;
    if (g >= 3584) return;
    half8 out;
    _Float16* dst;
    if (g < 512) {
        int t8 = g >> 6, l = g & 63;
#pragma unroll
        for (int j = 0; j < 8; j++)
            out[j] = (_Float16)WcUT[((l >> 4) * 8 + j) * 128 + t8 * 16 + (l & 15)];
        dst = &fragWcU[g * 8];
    } else if (g < 1536) {
        int g2 = g - 512;
        int t8 = g2 >> 7, s = (g2 >> 6) & 1, l = g2 & 63;
#pragma unroll
        for (int j = 0; j < 8; j++)
            out[j] = (_Float16)WcMT[(s * 32 + (l >> 4) * 8 + j) * 128 + t8 * 16 + (l & 15)];
        dst = &fragWcM[g2 * 8];
    } else {
        int g2 = g - 1536;
        int t8 = g2 >> 8, s = (g2 >> 6) & 3, l = g2 & 63;
#pragma unroll
        for (int j = 0; j < 8; j++)
            out[j] = (_Float16)W2T[(s * 32 + (l >> 4) * 8 + j) * 128 + t8 * 16 + (l & 15)];
        dst = &fragW2[g2 * 8];
    }
    *(half8*)dst = out;
}

// ============ fp16 PRE-SCALED user features: xs16[n] = dinv[n] * x_user[n] ============

__global__ void k_half(const float* __restrict__ x, const float* __restrict__ dinv,
                       __half2* __restrict__ o, int n2) {
    int i = blockIdx.x * 256 + threadIdx.x;
    if (i < n2) {
        float2 v = ((const float2*)x)[i];
        float s = dinv[i >> 4];   // 16 half2 per node
        o[i] = __floats2half2_rn(v.x * s, v.y * s);
    }
}

// ============ layer-1 aggregation in raw 32-dim feature space ============
__global__ void k_agg1(const __half2* __restrict__ xs16, const float* __restrict__ x_user,
                       const int* __restrict__ offsets, const unsigned short* __restrict__ csr,
                       const float* __restrict__ dinv,
                       float* __restrict__ gfull, float* __restrict__ beta) {
    int t = threadIdx.x;
    int l = t & 63, w = t >> 6;
    int n = blockIdx.x * 4 + w;
    int sub = l >> 4, fp = l & 15;   // 4 subgroups x 16 half2-features
    int s = offsets[n], e = offsets[n + 1];
    float2 acc = make_float2(0.f, 0.f);
    float sacc = 0.f;
    int j = s + sub;
    for (; j + 4 < e; j += 8) {
        int r0 = csr[j], r1 = csr[j + 4];
        float2 a = __half22float2(xs16[r0 * 16 + fp]);
        float2 b = __half22float2(xs16[r1 * 16 + fp]);
        acc.x += a.x + b.x;
        acc.y += a.y + b.y;
        if (fp == 0) sacc += dinv[r0] + dinv[r1];
    }
    if (j < e) {
        int r0 = csr[j];
        float2 a = __half22float2(xs16[r0 * 16 + fp]);
        acc.x += a.x; acc.y += a.y;
        if (fp == 0) sacc += dinv[r0];
    }
    acc.x += __shfl_xor(acc.x, 16, 64); acc.y += __shfl_xor(acc.y, 16, 64);
    acc.x += __shfl_xor(acc.x, 32, 64); acc.y += __shfl_xor(acc.y, 32, 64);
    sacc += __shfl_xor(sacc, 16, 64);
    sacc += __shfl_xor(sacc, 32, 64);
    float dn = dinv[n];
    if (l < 16) {
        float2 xv = ((const float2*)x_user)[n * 16 + l];
        float2 o;
        o.x = dn * dn * xv.x + dn * acc.x;
        o.y = dn * dn * xv.y + dn * acc.y;
        ((float2*)gfull)[n * 16 + l] = o;
    }
    if (l == 0) beta[n] = dn * dn + dn * sacc;
}

// ============ fused user chain (MFMA) -> SLICED fp16 table h2s[4][NU][32] ============
__global__ void __launch_bounds__(256) k_user(
        const float* __restrict__ gfull, const float* __restrict__ beta,
        const _Float16* __restrict__ fragWcU, const float* __restrict__ bcU,
        const _Float16* __restrict__ fragW2, const float* __restrict__ b2,
        const float* __restrict__ dinv, _Float16* __restrict__ h2s) {
    __shared__ _Float16 xs[64 * 40];   // 64 rows x K=32 (pad 40)
    __shared__ _Float16 ys[64 * 136];  // 64 rows x 128 (pad 136)
    int t = threadIdx.x;
    int n0 = blockIdx.x * 64;
    {
        int r = t >> 2, c0 = (t & 3) * 8;
        int n = n0 + r;
        float4 a = make_float4(0.f, 0.f, 0.f, 0.f), b = a;
        if (n < NU) {
            const float4* g4 = (const float4*)gfull;
            a = g4[n * 8 + (c0 >> 2)];
            b = g4[n * 8 + (c0 >> 2) + 1];
        }
        half8 h;
        h[0] = (_Float16)a.x; h[1] = (_Float16)a.y; h[2] = (_Float16)a.z; h[3] = (_Float16)a.w;
        h[4] = (_Float16)b.x; h[5] = (_Float16)b.y; h[6] = (_Float16)b.z; h[7] = (_Float16)b.w;
        *(half8*)&xs[r * 40 + c0] = h;
    }
    __syncthreads();
    int l = t & 63, w = t >> 6;
    int lr = l & 15, lq = l >> 4;
    half8 af = *(half8*)&xs[(16 * w + lr) * 40 + lq * 8];
    const half8* fU = (const half8*)fragWcU;
    f32x4 zero = {0.f, 0.f, 0.f, 0.f};
    f32x4 acc[8];
#pragma unroll
    for (int t8 = 0; t8 < 8; t8++) {
        half8 bf = fU[t8 * 64 + l];
        acc[t8] = __builtin_amdgcn_mfma_f32_16x16x32_f16(af, bf, zero, 0, 0, 0);
    }
    float betav[4];
#pragma unroll
    for (int r = 0; r < 4; r++) {
        int n = n0 + 16 * w + lq * 4 + r;
        betav[r] = (n < NU) ? beta[n] : 0.f;
    }
#pragma unroll
    for (int t8 = 0; t8 < 8; t8++) {
        float bc = bcU[16 * t8 + lr];
#pragma unroll
        for (int r = 0; r < 4; r++) {
            float v = fmaxf(acc[t8][r] + betav[r] * bc, 0.f);
            ys[(16 * w + lq * 4 + r) * 136 + 16 * t8 + lr] = (_Float16)v;
        }
    }
    __syncthreads();
    f32x4 acc2[8];
#pragma unroll
    for (int t8 = 0; t8 < 8; t8++) acc2[t8] = zero;
    const half8* fW = (const half8*)fragW2;
#pragma unroll
    for (int s = 0; s < 4; s++) {
        half8 a2 = *(half8*)&ys[(16 * w + lr) * 136 + s * 32 + lq * 8];
#pragma unroll
        for (int t8 = 0; t8 < 8; t8++) {
            half8 bf = fW[(t8 * 4 + s) * 64 + l];
            acc2[t8] = __builtin_amdgcn_mfma_f32_16x16x32_f16(a2, bf, acc2[t8], 0, 0, 0);
        }
    }
#pragma unroll
    for (int r = 0; r < 4; r++) {
        int n = n0 + 16 * w + lq * 4 + r;
        if (n < NU) {
            float s = dinv[n];
#pragma unroll
            for (int t8 = 0; t8 < 8; t8++) {
                int c = 16 * t8 + lr;
                // sliced layout: slice = c>>5 (32-ch slices), within-slice c&31
                h2s[(size_t)(c >> 5) * (NU * 32) + n * 32 + (c & 31)] =
                    (_Float16)((acc2[t8][r] + b2[c]) * s);
            }
        }
    }
}

// ============ fused movie chain (MFMA) -> fp16 relu'd h2m16[NM][128] ============
__global__ void __launch_bounds__(256) k_movie(
        const float* __restrict__ xm,
        const _Float16* __restrict__ fragWcM, const float* __restrict__ bcM,
        const _Float16* __restrict__ fragW2, const float* __restrict__ b2,
        _Float16* __restrict__ h2m16) {
    __shared__ _Float16 xs[64 * 72];   // 64 rows x K=64 (pad 72)
    __shared__ _Float16 ys[64 * 136];
    int t = threadIdx.x;
    int n0 = blockIdx.x * 64;
    {
        int r = t >> 2, c0 = (t & 3) * 16;
        int n = n0 + r;
        float4 a = make_float4(0.f, 0.f, 0.f, 0.f), b = a, c = a, d = a;
        if (n < NM) {
            const float4* g4 = (const float4*)xm;
            a = g4[n * 16 + (c0 >> 2)];
            b = g4[n * 16 + (c0 >> 2) + 1];
            c = g4[n * 16 + (c0 >> 2) + 2];
            d = g4[n * 16 + (c0 >> 2) + 3];
        }
        half8 h0, h1;
        h0[0] = (_Float16)a.x; h0[1] = (_Float16)a.y; h0[2] = (_Float16)a.z; h0[3] = (_Float16)a.w;
        h0[4] = (_Float16)b.x; h0[5] = (_Float16)b.y; h0[6] = (_Float16)b.z; h0[7] = (_Float16)b.w;
        h1[0] = (_Float16)c.x; h1[1] = (_Float16)c.y; h1[2] = (_Float16)c.z; h1[3] = (_Float16)c.w;
        h1[4] = (_Float16)d.x; h1[5] = (_Float16)d.y; h1[6] = (_Float16)d.z; h1[7] = (_Float16)d.w;
        *(half8*)&xs[r * 72 + c0] = h0;
        *(half8*)&xs[r * 72 + c0 + 8] = h1;
    }
    __syncthreads();
    int l = t & 63, w = t >> 6;
    int lr = l & 15, lq = l >> 4;
    const half8* fM = (const half8*)fragWcM;
    f32x4 zero = {0.f, 0.f, 0.f, 0.f};
    f32x4 acc[8];
#pragma unroll
    for (int t8 = 0; t8 < 8; t8++) acc[t8] = zero;
#pragma unroll
    for (int s = 0; s < 2; s++) {
        half8 af = *(half8*)&xs[(16 * w + lr) * 72 + s * 32 + lq * 8];
#pragma unroll
        for (int t8 = 0; t8 < 8; t8++) {
            half8 bf = fM[(t8 * 2 + s) * 64 + l];
            acc[t8] = __builtin_amdgcn_mfma_f32_16x16x32_f16(af, bf, acc[t8], 0, 0, 0);
        }
    }
#pragma unroll
    for (int t8 = 0; t8 < 8; t8++) {
        float bc = bcM[16 * t8 + lr];
#pragma unroll
        for (int r = 0; r < 4; r++) {
            float v = fmaxf(acc[t8][r] + bc, 0.f);
            ys[(16 * w + lq * 4 + r) * 136 + 16 * t8 + lr] = (_Float16)v;
        }
    }
    __syncthreads();
    f32x4 acc2[8];
#pragma unroll
    for (int t8 = 0; t8 < 8; t8++) acc2[t8] = zero;
    const half8* fW = (const half8*)fragW2;
#pragma unroll
    for (int s = 0; s < 4; s++) {
        half8 a2 = *(half8*)&ys[(16 * w + lr) * 136 + s * 32 + lq * 8];
#pragma unroll
        for (int t8 = 0; t8 < 8; t8++) {
            half8 bf = fW[(t8 * 4 + s) * 64 + l];
            acc2[t8] = __builtin_amdgcn_mfma_f32_16x16x32_f16(a2, bf, acc2[t8], 0, 0, 0);
        }
    }
#pragma unroll
    for (int r = 0; r < 4; r++) {
        int n = n0 + 16 * w + lq * 4 + r;
        if (n < NM) {
#pragma unroll
            for (int t8 = 0; t8 < 8; t8++) {
                int c = 16 * t8 + lr;
                // pre-relu'd fp16 (x2_m only feeds relu->projection)
                h2m16[(size_t)n * 128 + c] = (_Float16)fmaxf(acc2[t8][r] + b2[c], 0.f);
            }
        }
    }
}

// ============ layer-2 aggregation, XCD-sliced: 4 slices x 32 ch ============
// block b: slice = (b&7)>>1 (XCD-local under %8 dispatch), group = (b>>3)*2 + (b&1)
// wave handles one dest node: 16 lanes/edge (half2 each), 4 edges per group, unroll 2.
// Partial projection over the slice's 32 channels -> atomicAdd into P[n][q].
__global__ void __launch_bounds__(256) k_agg2(
        const _Float16* __restrict__ h2s, const int* __restrict__ offsets,
        const unsigned short* __restrict__ csr, const float* __restrict__ dinv,
        const float* __restrict__ We, float* __restrict__ P) {
    int b = blockIdx.x;
    int slice = (b & 7) >> 1;
    int grp = (b >> 3) * 2 + (b & 1);
    int t = threadIdx.x;
    int l = t & 63, w = t >> 6;
    int n = grp * 4 + w;
    int eidx = l >> 4, c2 = l & 15;   // edge-in-group, channel-pair
    const __half2* tab = (const __half2*)h2s + (size_t)slice * (NU * 16);
    int s = offsets[n], e = offsets[n + 1];
    float2 acc = make_float2(0.f, 0.f);
    for (int j0 = s; j0 < e; j0 += 8) {
        int j1 = j0 + eidx, j2 = j0 + 4 + eidx;
        if (j1 < e) {
            int r = csr[j1];
            float2 v = __half22float2(tab[r * 16 + c2]);
            acc.x += v.x; acc.y += v.y;
        }
        if (j2 < e) {
            int r = csr[j2];
            float2 v = __half22float2(tab[r * 16 + c2]);
            acc.x += v.x; acc.y += v.y;
        }
    }
    if (eidx == 0) {  // self term (table pre-scaled by dinv[n])
        float2 v = __half22float2(tab[n * 16 + c2]);
        acc.x += v.x; acc.y += v.y;
    }
    // reduce over the 4 edge groups
    acc.x += __shfl_xor(acc.x, 16, 64); acc.y += __shfl_xor(acc.y, 16, 64);
    acc.x += __shfl_xor(acc.x, 32, 64); acc.y += __shfl_xor(acc.y, 32, 64);
    float dn = dinv[n];
    float v0 = fmaxf(acc.x * dn, 0.f);
    float v1 = fmaxf(acc.y * dn, 0.f);
    float p[NC];
#pragma unroll
    for (int q = 0; q < NC; q++) {
        float2 wv = *(const float2*)&We[q * 256 + slice * 32 + 2 * c2];
        p[q] = wv.x * v0 + wv.y * v1;
    }
    // reduce over the 16 channel-pairs
#pragma unroll
    for (int q = 0; q < NC; q++) {
#pragma unroll
        for (int d = 8; d >= 1; d >>= 1) p[q] += __shfl_xor(p[q], d, 64);
    }
    if (l == 0) {
#pragma unroll
        for (int q = 0; q < NC; q++) atomicAdd(&P[n * NC + q], p[q]);
    }
}

// ============ movie projection from relu'd fp16: P_m = We_m . h2m ============
__global__ void k_mproj(const __half2* __restrict__ h2m16, const float* __restrict__ We,
                        float* __restrict__ P) {
    int t = threadIdx.x;
    int l = t & 63, w = t >> 6;
    int n = blockIdx.x * 4 + w;   // movie-local index
    float2 xv = __half22float2(h2m16[n * 64 + l]);
    float p[NC];
#pragma unroll
    for (int q = 0; q < NC; q++) {
        float2 wv = *(const float2*)&We[q * 256 + 128 + 2 * l];
        p[q] = wv.x * xv.x + wv.y * xv.y;
    }
#pragma unroll
    for (int q = 0; q < NC; q++) {
#pragma unroll
        for (int d = 32; d >= 1; d >>= 1) p[q] += __shfl_xor(p[q], d, 64);
    }
    if (l == 0) {
#pragma unroll
        for (int q = 0; q < NC; q++) P[(NU + n) * NC + q] = p[q];
    }
}

// ============ edge output: out[e] = P[row[e]] + P[NU + col[e]] + be ============
__global__ void k_edge_out(const int* __restrict__ row, const int* __restrict__ col,
                           const float* __restrict__ P, const float* __restrict__ be,
                           float* __restrict__ out, int E) {
    __shared__ float ls[256 * 11];
    int t = threadIdx.x;
    int e0 = blockIdx.x * 256;
    int e = e0 + t;
    if (e < E) {
        int r = row[e], c = col[e];
        const float2* pu = (const float2*)(P + (size_t)r * NC);
        const float2* pm = (const float2*)(P + (size_t)(NU + c) * NC);
        const float2* be2 = (const float2*)be;
#pragma unroll
        for (int q = 0; q < 5; q++) {
            float2 a = pu[q], b = pm[q], bb = be2[q];
            ls[t * 11 + 2 * q] = a.x + b.x + bb.x;
            ls[t * 11 + 2 * q + 1] = a.y + b.y + bb.y;
        }
    }
    __syncthreads();
    int nvals = (E - e0 < 256 ? E - e0 : 256) * NC;
    size_t base = (size_t)e0 * NC;
    for (int k = t; k < nvals; k += 256) {
        int ee = k / NC, q = k - ee * NC;
        out[base + k] = ls[ee * 11 + q];
    }
}

extern "C" void kernel_launch(void* const* d_in, const int* in_sizes, int n_in,
                              void* d_out, int out_size, void* d_ws, size_t ws_size,
                              hipStream_t stream) {
    const float* x_user  = (const float*)d_in[0];
    const float* x_movie = (const float*)d_in[1];
    const int*   ei      = (const int*)d_in[2];
    const float* Wu = (const float*)d_in[3];
    const float* bu = (const float*)d_in[4];
    const float* Wm = (const float*)d_in[5];
    const float* bm = (const float*)d_in[6];
    const float* W1 = (const float*)d_in[7];
    const float* b1 = (const float*)d_in[8];
    const float* W2 = (const float*)d_in[9];
    const float* b2 = (const float*)d_in[10];
    const float* We = (const float*)d_in[11];
    const float* be = (const float*)d_in[12];
    float* out = (float*)d_out;

    int E = in_sizes[2] / 2;
    const int* row = ei;
    const int* col = ei + E;

    char* p = (char*)d_ws;
    auto alloc = [&](size_t bytes) -> void* {
        void* r = (void*)p;
        p += (bytes + 255) & ~(size_t)255;
        return r;
    };
    int*            counts     = (int*)alloc((size_t)NU * 4);
    int*            offsets    = (int*)alloc((size_t)(NU + 1) * 4);
    unsigned short* csr16      = (unsigned short*)alloc((size_t)E * 2);
    unsigned int*   pairs      = (unsigned int*)alloc((size_t)NB * CAP * 4);
    int*            bucket_cur = (int*)alloc((size_t)NB * 4);
    float*          dinv       = (float*)alloc((size_t)NU * 4);
    float*          beta       = (float*)alloc((size_t)NU * 4);
    int*            sums       = (int*)alloc((size_t)256 * 4);
    float*          WcUT       = (float*)alloc((size_t)FU * HD * 4);
    float*          WcMT       = (float*)alloc((size_t)FM * HD * 4);
    float*          W2T        = (float*)alloc((size_t)HD * HD * 4);
    float*          bcU        = (float*)alloc((size_t)HD * 4);
    float*          bcM       = (float*)alloc((size_t)HD * 4);
    _Float16*       fragWcU    = (_Float16*)alloc((size_t)4096 * 2);
    _Float16*       fragWcM    = (_Float16*)alloc((size_t)8192 * 2);
    _Float16*       fragW2     = (_Float16*)alloc((size_t)16384 * 2);
    __half2*        xs16       = (__half2*)alloc((size_t)NU * FU * 2);
    float*          gfull      = (float*)alloc((size_t)NU * FU * 4);
    _Float16*       h2s        = (_Float16*)alloc((size_t)NU * HD * 2);   // [4][NU][32]
    _Float16*       h2m16      = (_Float16*)alloc((size_t)NM * HD * 2);
    float*          P          = (float*)alloc((size_t)NN * NC * 4);

    const int tb = 256;
    const int nscan = (NU + 255) / 256;  // 196

    hipMemsetAsync(bucket_cur, 0, (size_t)NB * 4, stream);
    hipMemsetAsync(P, 0, (size_t)NU * NC * 4, stream);  // user part accumulated atomically
    k_bucket<<<(E + CHUNK - 1) / CHUNK, 256, 0, stream>>>(row, col, E, bucket_cur, pairs);
    k_bcount<<<NB, 256, 0, stream>>>(pairs, bucket_cur, counts);
    k_scanA<<<nscan, 256, 0, stream>>>(counts, sums);
    k_scanB<<<1, 256, 0, stream>>>(sums, nscan, offsets);
    k_scanC<<<nscan, 256, 0, stream>>>(counts, sums, offsets, dinv);
    k_scatter<<<NB, 256, 0, stream>>>(pairs, bucket_cur, offsets, csr16);

    k_fold<<<113, 256, 0, stream>>>(Wu, bu, Wm, bm, W1, b1, W2, WcUT, bcU, WcMT, bcM, W2T);
    k_wfrag<<<14, 256, 0, stream>>>(WcUT, WcMT, W2T, fragWcU, fragWcM, fragW2);
    k_half<<<(NU * FU / 2 + 255) / 256, 256, 0, stream>>>(x_user, dinv, xs16, NU * FU / 2);

    k_agg1<<<NU / 4, 256, 0, stream>>>(xs16, x_user, offsets, csr16, dinv, gfull, beta);

    k_user<<<(NU + 63) / 64, 256, 0, stream>>>(gfull, beta, fragWcU, bcU, fragW2, b2, dinv, h2s);
    k_movie<<<(NM + 63) / 64, 256, 0, stream>>>(x_movie, fragWcM, bcM, fragW2, b2, h2m16);

    // 8 * 6250 blocks: slice = (b&7)>>1 pins each slice to (heuristically) 2 XCDs
    k_agg2<<<50000, 256, 0, stream>>>(h2s, offsets, csr16, dinv, We, P);
    k_mproj<<<NM / 4, 256, 0, stream>>>((const __half2*)h2m16, We, P);

    k_edge_out<<<(E + tb - 1) / tb, tb, 0, stream>>>(row, col, P, be, out, E);
}

// Round 8
// 411.319 us; speedup vs baseline: 1.1442x; 1.1442x over previous
//
#include <hip/hip_runtime.h>
#include <hip/hip_fp16.h>

#define NU 50000
#define NM 50000
#define NN 100000
#define FU 32
#define FM 64
#define HD 128
#define NC 10

#define NB 196      // buckets of 256 destination cols
#define CAP 8192    // per-bucket staging capacity
#define CHUNK 1024  // edges per k_bucket block

typedef __attribute__((ext_vector_type(8))) _Float16 half8;
typedef __attribute__((ext_vector_type(4))) float f32x4;

// ============ scan helpers ============

__device__ inline int wave_incl_scan(int x, int l) {
#pragma unroll
    for (int d = 1; d < 64; d <<= 1) {
        int u = __shfl_up(x, d, 64);
        if (l >= d) x += u;
    }
    return x;
}

template <int NWAVE>
__device__ inline int block_excl_scan(int v, int t, int* wsum, int* out_total) {
    int l = t & 63, w = t >> 6;
    int inc = wave_incl_scan(v, l);
    if (l == 63) wsum[w] = inc;
    __syncthreads();
    int base = 0;
    int tot = 0;
#pragma unroll
    for (int i = 0; i < NWAVE; i++) {
        int s = wsum[i];
        if (i < w) base += s;
        tot += s;
    }
    if (out_total) *out_total = tot;
    return base + inc - v;
}

// ============ bucketed CSR build ============
// pairs[b*CAP + i] = row | (col<<16), grouped by bucket b = col>>8

__global__ void k_bucket(const int* __restrict__ row, const int* __restrict__ col, int E,
                         int* __restrict__ bucket_cur, unsigned int* __restrict__ pairs) {
    __shared__ int hist[NB];
    __shared__ int lofs[NB];
    __shared__ int gbase[NB];
    __shared__ int lcur[NB];
    __shared__ int wsum[4];
    __shared__ unsigned int stage[CHUNK];
    int t = threadIdx.x;
    int e0 = blockIdx.x * CHUNK;
    int cnt = min(CHUNK, E - e0);
    for (int i = t; i < NB; i += 256) hist[i] = 0;
    __syncthreads();
    unsigned int pk[CHUNK / 256];
#pragma unroll
    for (int i = 0; i < CHUNK / 256; i++) {
        int k = i * 256 + t;
        if (k < cnt) {
            unsigned int r = (unsigned int)row[e0 + k];
            unsigned int c = (unsigned int)col[e0 + k];
            pk[i] = r | (c << 16);
            atomicAdd(&hist[c >> 8], 1);
        }
    }
    __syncthreads();
    int v = (t < NB) ? hist[t] : 0;
    int excl = block_excl_scan<4>(v, t, wsum, nullptr);
    if (t < NB) {
        lofs[t] = excl;
        lcur[t] = excl;
        gbase[t] = atomicAdd(&bucket_cur[t], v);
    }
    __syncthreads();
#pragma unroll
    for (int i = 0; i < CHUNK / 256; i++) {
        int k = i * 256 + t;
        if (k < cnt) {
            int pos = atomicAdd(&lcur[pk[i] >> 24], 1);  // (c>>8) == pk>>24
            stage[pos] = pk[i];
        }
    }
    __syncthreads();
    int w = t >> 6, l = t & 63;
    for (int b = w; b < NB; b += 4) {
        int start = lofs[b], n = hist[b];
        unsigned int g = (unsigned int)b * CAP + (unsigned int)gbase[b];
        for (int i = l; i < n; i += 64) pairs[g + i] = stage[start + i];
    }
}

// per-col degree counts from bucketed pairs (one block per bucket)
__global__ void k_bcount(const unsigned int* __restrict__ pairs,
                         const int* __restrict__ bucket_cur, int* __restrict__ counts) {
    __shared__ int lc[256];
    int b = blockIdx.x, t = threadIdx.x;
    lc[t] = 0;
    __syncthreads();
    int n = bucket_cur[b];
    unsigned int base = (unsigned int)b * CAP;
    for (int i = t; i < n; i += 256) {
        unsigned int c = pairs[base + i] >> 16;
        atomicAdd(&lc[c & 255], 1);
    }
    __syncthreads();
    int col0 = b << 8;
    if (col0 + t < NU) counts[col0 + t] = lc[t];
}

__global__ void k_scanA(const int* __restrict__ counts, int* __restrict__ sums) {
    __shared__ int wsum[4];
    int t = threadIdx.x;
    int idx = blockIdx.x * 256 + t;
    int v = (idx < NU) ? counts[idx] : 0;
    int total;
    block_excl_scan<4>(v, t, wsum, &total);
    if (t == 0) sums[blockIdx.x] = total;
}

__global__ void k_scanB(int* __restrict__ sums, int nblk, int* __restrict__ offsets) {
    __shared__ int wsum[4];
    int t = threadIdx.x;  // 256
    int v = (t < nblk) ? sums[t] : 0;
    int total;
    int excl = block_excl_scan<4>(v, t, wsum, &total);
    if (t < nblk) sums[t] = excl;
    if (t == 0) offsets[NU] = total;
}

__global__ void k_scanC(const int* __restrict__ counts, const int* __restrict__ sums,
                        int* __restrict__ offsets, float* __restrict__ dinv) {
    __shared__ int wsum[4];
    int t = threadIdx.x;
    int idx = blockIdx.x * 256 + t;
    int v = (idx < NU) ? counts[idx] : 0;
    int excl = block_excl_scan<4>(v, t, wsum, nullptr);
    if (idx < NU) {
        offsets[idx] = sums[blockIdx.x] + excl;
        dinv[idx] = rsqrtf((float)(v + 1));
    }
}

// scatter within bucket window (one block per bucket); csr stored as u16
__global__ void k_scatter(const unsigned int* __restrict__ pairs,
                          const int* __restrict__ bucket_cur, const int* __restrict__ offsets,
                          unsigned short* __restrict__ csr16) {
    __shared__ int lcur[256];
    int b = blockIdx.x, t = threadIdx.x;
    int col0 = b << 8;
    lcur[t] = (col0 + t < NU) ? offsets[col0 + t] : 0;
    __syncthreads();
    int n = bucket_cur[b];
    unsigned int base = (unsigned int)b * CAP;
    for (int i = t; i < n; i += 256) {
        unsigned int pk = pairs[base + i];
        int pos = atomicAdd(&lcur[(pk >> 16) & 255], 1);
        csr16[pos] = (unsigned short)(pk & 0xffffu);
    }
}

// ============ weight folding ============

__global__ void k_fold(const float* __restrict__ Wu, const float* __restrict__ bu,
                       const float* __restrict__ Wm, const float* __restrict__ bm,
                       const float* __restrict__ W1, const float* __restrict__ b1,
                       const float* __restrict__ W2,
                       float* __restrict__ WcUT, float* __restrict__ bcU,
                       float* __restrict__ WcMT, float* __restrict__ bcM,
                       float* __restrict__ W2T) {
    int bid = blockIdx.x, t = threadIdx.x;
    if (bid < 16) {                       // WcUT[k][c], k<32, c<128
        int f = bid * 256 + t;
        int k = f >> 7, c = f & 127;
        float s = 0.f;
        for (int j = 0; j < 128; j++) s += W1[c * 128 + j] * Wu[j * 32 + k];
        WcUT[f] = s;
    } else if (bid < 48) {                // WcMT[k][c], k<64
        int f = (bid - 16) * 256 + t;
        int k = f >> 7, c = f & 127;
        float s = 0.f;
        for (int j = 0; j < 128; j++) s += W1[c * 128 + j] * Wm[j * 64 + k];
        WcMT[f] = s;
    } else if (bid < 112) {               // W2T[k][c] = W2[c][k]
        int f = (bid - 48) * 256 + t;
        int k = f >> 7, c = f & 127;
        W2T[f] = W2[c * 128 + k];
    } else {
        if (t < 128) {
            float s = 0.f;
            for (int j = 0; j < 128; j++) s += W1[t * 128 + j] * bu[j];
            bcU[t] = s + b1[t];
        } else if (t < 256) {
            int c = t - 128;
            float s = 0.f;
            for (int j = 0; j < 128; j++) s += W1[c * 128 + j] * bm[j];
            bcM[c] = s + b1[c];
        }
    }
}

// ============ MFMA B-fragment tables (fp16, lane-ordered) ============
__global__ void k_wfrag(const float* __restrict__ WcUT, const float* __restrict__ WcMT,
                        const float* __restrict__ W2T,
                        _Float16* __restrict__ fragWcU, _Float16* __restrict__ fragWcM,
                        _Float16* __restrict__ fragW2) {
    int g = blockIdx.x * 256 + threadIdx.x;
    if (g >= 3584) return;
    half8 out;
    _Float16* dst;
    if (g < 512) {
        int t8 = g >> 6, l = g & 63;
#pragma unroll
        for (int j = 0; j < 8; j++)
            out[j] = (_Float16)WcUT[((l >> 4) * 8 + j) * 128 + t8 * 16 + (l & 15)];
        dst = &fragWcU[g * 8];
    } else if (g < 1536) {
        int g2 = g - 512;
        int t8 = g2 >> 7, s = (g2 >> 6) & 1, l = g2 & 63;
#pragma unroll
        for (int j = 0; j < 8; j++)
            out[j] = (_Float16)WcMT[(s * 32 + (l >> 4) * 8 + j) * 128 + t8 * 16 + (l & 15)];
        dst = &fragWcM[g2 * 8];
    } else {
        int g2 = g - 1536;
        int t8 = g2 >> 8, s = (g2 >> 6) & 3, l = g2 & 63;
#pragma unroll
        for (int j = 0; j < 8; j++)
            out[j] = (_Float16)W2T[(s * 32 + (l >> 4) * 8 + j) * 128 + t8 * 16 + (l & 15)];
        dst = &fragW2[g2 * 8];
    }
    *(half8*)dst = out;
}

// ============ fp16 PRE-SCALED user features: xs16[n] = dinv[n] * x_user[n] ============

__global__ void k_half(const float* __restrict__ x, const float* __restrict__ dinv,
                       __half2* __restrict__ o, int n2) {
    int i = blockIdx.x * 256 + threadIdx.x;
    if (i < n2) {
        float2 v = ((const float2*)x)[i];
        float s = dinv[i >> 4];   // 16 half2 per node
        o[i] = __floats2half2_rn(v.x * s, v.y * s);
    }
}

// ============ layer-1 aggregation in raw 32-dim feature space ============
__global__ void k_agg1(const __half2* __restrict__ xs16, const float* __restrict__ x_user,
                       const int* __restrict__ offsets, const unsigned short* __restrict__ csr,
                       const float* __restrict__ dinv,
                       float* __restrict__ gfull, float* __restrict__ beta) {
    int t = threadIdx.x;
    int l = t & 63, w = t >> 6;
    int n = blockIdx.x * 4 + w;
    int sub = l >> 4, fp = l & 15;   // 4 subgroups x 16 half2-features
    int s = offsets[n], e = offsets[n + 1];
    float2 acc = make_float2(0.f, 0.f);
    float sacc = 0.f;
    int j = s + sub;
    for (; j + 4 < e; j += 8) {
        int r0 = csr[j], r1 = csr[j + 4];
        float2 a = __half22float2(xs16[r0 * 16 + fp]);
        float2 b = __half22float2(xs16[r1 * 16 + fp]);
        acc.x += a.x + b.x;
        acc.y += a.y + b.y;
        if (fp == 0) sacc += dinv[r0] + dinv[r1];
    }
    if (j < e) {
        int r0 = csr[j];
        float2 a = __half22float2(xs16[r0 * 16 + fp]);
        acc.x += a.x; acc.y += a.y;
        if (fp == 0) sacc += dinv[r0];
    }
    acc.x += __shfl_xor(acc.x, 16, 64); acc.y += __shfl_xor(acc.y, 16, 64);
    acc.x += __shfl_xor(acc.x, 32, 64); acc.y += __shfl_xor(acc.y, 32, 64);
    sacc += __shfl_xor(sacc, 16, 64);
    sacc += __shfl_xor(sacc, 32, 64);
    float dn = dinv[n];
    if (l < 16) {
        float2 xv = ((const float2*)x_user)[n * 16 + l];
        float2 o;
        o.x = dn * dn * xv.x + dn * acc.x;
        o.y = dn * dn * xv.y + dn * acc.y;
        ((float2*)gfull)[n * 16 + l] = o;
    }
    if (l == 0) beta[n] = dn * dn + dn * sacc;
}

// ============ fused user chain (MFMA) -> SLICED fp16 table h2s[4][NU][32] ============
__global__ void __launch_bounds__(256) k_user(
        const float* __restrict__ gfull, const float* __restrict__ beta,
        const _Float16* __restrict__ fragWcU, const float* __restrict__ bcU,
        const _Float16* __restrict__ fragW2, const float* __restrict__ b2,
        const float* __restrict__ dinv, _Float16* __restrict__ h2s) {
    __shared__ _Float16 xs[64 * 40];   // 64 rows x K=32 (pad 40)
    __shared__ _Float16 ys[64 * 136];  // 64 rows x 128 (pad 136)
    int t = threadIdx.x;
    int n0 = blockIdx.x * 64;
    {
        int r = t >> 2, c0 = (t & 3) * 8;
        int n = n0 + r;
        float4 a = make_float4(0.f, 0.f, 0.f, 0.f), b = a;
        if (n < NU) {
            const float4* g4 = (const float4*)gfull;
            a = g4[n * 8 + (c0 >> 2)];
            b = g4[n * 8 + (c0 >> 2) + 1];
        }
        half8 h;
        h[0] = (_Float16)a.x; h[1] = (_Float16)a.y; h[2] = (_Float16)a.z; h[3] = (_Float16)a.w;
        h[4] = (_Float16)b.x; h[5] = (_Float16)b.y; h[6] = (_Float16)b.z; h[7] = (_Float16)b.w;
        *(half8*)&xs[r * 40 + c0] = h;
    }
    __syncthreads();
    int l = t & 63, w = t >> 6;
    int lr = l & 15, lq = l >> 4;
    half8 af = *(half8*)&xs[(16 * w + lr) * 40 + lq * 8];
    const half8* fU = (const half8*)fragWcU;
    f32x4 zero = {0.f, 0.f, 0.f, 0.f};
    f32x4 acc[8];
#pragma unroll
    for (int t8 = 0; t8 < 8; t8++) {
        half8 bf = fU[t8 * 64 + l];
        acc[t8] = __builtin_amdgcn_mfma_f32_16x16x32_f16(af, bf, zero, 0, 0, 0);
    }
    float betav[4];
#pragma unroll
    for (int r = 0; r < 4; r++) {
        int n = n0 + 16 * w + lq * 4 + r;
        betav[r] = (n < NU) ? beta[n] : 0.f;
    }
#pragma unroll
    for (int t8 = 0; t8 < 8; t8++) {
        float bc = bcU[16 * t8 + lr];
#pragma unroll
        for (int r = 0; r < 4; r++) {
            float v = fmaxf(acc[t8][r] + betav[r] * bc, 0.f);
            ys[(16 * w + lq * 4 + r) * 136 + 16 * t8 + lr] = (_Float16)v;
        }
    }
    __syncthreads();
    f32x4 acc2[8];
#pragma unroll
    for (int t8 = 0; t8 < 8; t8++) acc2[t8] = zero;
    const half8* fW = (const half8*)fragW2;
#pragma unroll
    for (int s = 0; s < 4; s++) {
        half8 a2 = *(half8*)&ys[(16 * w + lr) * 136 + s * 32 + lq * 8];
#pragma unroll
        for (int t8 = 0; t8 < 8; t8++) {
            half8 bf = fW[(t8 * 4 + s) * 64 + l];
            acc2[t8] = __builtin_amdgcn_mfma_f32_16x16x32_f16(a2, bf, acc2[t8], 0, 0, 0);
        }
    }
#pragma unroll
    for (int r = 0; r < 4; r++) {
        int n = n0 + 16 * w + lq * 4 + r;
        if (n < NU) {
            float s = dinv[n];
#pragma unroll
            for (int t8 = 0; t8 < 8; t8++) {
                int c = 16 * t8 + lr;
                // sliced layout: slice = c>>5 (32-ch slices), within-slice c&31
                h2s[(size_t)(c >> 5) * (NU * 32) + n * 32 + (c & 31)] =
                    (_Float16)((acc2[t8][r] + b2[c]) * s);
            }
        }
    }
}

// ============ fused movie chain (MFMA) -> fp16 relu'd h2m16[NM][128] ============
__global__ void __launch_bounds__(256) k_movie(
        const float* __restrict__ xm,
        const _Float16* __restrict__ fragWcM, const float* __restrict__ bcM,
        const _Float16* __restrict__ fragW2, const float* __restrict__ b2,
        _Float16* __restrict__ h2m16) {
    __shared__ _Float16 xs[64 * 72];   // 64 rows x K=64 (pad 72)
    __shared__ _Float16 ys[64 * 136];
    int t = threadIdx.x;
    int n0 = blockIdx.x * 64;
    {
        int r = t >> 2, c0 = (t & 3) * 16;
        int n = n0 + r;
        float4 a = make_float4(0.f, 0.f, 0.f, 0.f), b = a, c = a, d = a;
        if (n < NM) {
            const float4* g4 = (const float4*)xm;
            a = g4[n * 16 + (c0 >> 2)];
            b = g4[n * 16 + (c0 >> 2) + 1];
            c = g4[n * 16 + (c0 >> 2) + 2];
            d = g4[n * 16 + (c0 >> 2) + 3];
        }
        half8 h0, h1;
        h0[0] = (_Float16)a.x; h0[1] = (_Float16)a.y; h0[2] = (_Float16)a.z; h0[3] = (_Float16)a.w;
        h0[4] = (_Float16)b.x; h0[5] = (_Float16)b.y; h0[6] = (_Float16)b.z; h0[7] = (_Float16)b.w;
        h1[0] = (_Float16)c.x; h1[1] = (_Float16)c.y; h1[2] = (_Float16)c.z; h1[3] = (_Float16)c.w;
        h1[4] = (_Float16)d.x; h1[5] = (_Float16)d.y; h1[6] = (_Float16)d.z; h1[7] = (_Float16)d.w;
        *(half8*)&xs[r * 72 + c0] = h0;
        *(half8*)&xs[r * 72 + c0 + 8] = h1;
    }
    __syncthreads();
    int l = t & 63, w = t >> 6;
    int lr = l & 15, lq = l >> 4;
    const half8* fM = (const half8*)fragWcM;
    f32x4 zero = {0.f, 0.f, 0.f, 0.f};
    f32x4 acc[8];
#pragma unroll
    for (int t8 = 0; t8 < 8; t8++) acc[t8] = zero;
#pragma unroll
    for (int s = 0; s < 2; s++) {
        half8 af = *(half8*)&xs[(16 * w + lr) * 72 + s * 32 + lq * 8];
#pragma unroll
        for (int t8 = 0; t8 < 8; t8++) {
            half8 bf = fM[(t8 * 2 + s) * 64 + l];
            acc[t8] = __builtin_amdgcn_mfma_f32_16x16x32_f16(af, bf, acc[t8], 0, 0, 0);
        }
    }
#pragma unroll
    for (int t8 = 0; t8 < 8; t8++) {
        float bc = bcM[16 * t8 + lr];
#pragma unroll
        for (int r = 0; r < 4; r++) {
            float v = fmaxf(acc[t8][r] + bc, 0.f);
            ys[(16 * w + lq * 4 + r) * 136 + 16 * t8 + lr] = (_Float16)v;
        }
    }
    __syncthreads();
    f32x4 acc2[8];
#pragma unroll
    for (int t8 = 0; t8 < 8; t8++) acc2[t8] = zero;
    const half8* fW = (const half8*)fragW2;
#pragma unroll
    for (int s = 0; s < 4; s++) {
        half8 a2 = *(half8*)&ys[(16 * w + lr) * 136 + s * 32 + lq * 8];
#pragma unroll
        for (int t8 = 0; t8 < 8; t8++) {
            half8 bf = fW[(t8 * 4 + s) * 64 + l];
            acc2[t8] = __builtin_amdgcn_mfma_f32_16x16x32_f16(a2, bf, acc2[t8], 0, 0, 0);
        }
    }
#pragma unroll
    for (int r = 0; r < 4; r++) {
        int n = n0 + 16 * w + lq * 4 + r;
        if (n < NM) {
#pragma unroll
            for (int t8 = 0; t8 < 8; t8++) {
                int c = 16 * t8 + lr;
                h2m16[(size_t)n * 128 + c] = (_Float16)fmaxf(acc2[t8][r] + b2[c], 0.f);
            }
        }
    }
}

// ============ layer-2 aggregation, XCD-sliced, NO atomics ============
// block b: slice = (b&7)>>1, grp = (b>>3)*2 + (b&1); wave = one dest node.
// Partial projection over the slice's 32 channels -> plain stores into
// Ppart[slice][n][10]; k_psum reduces the 4 slices.
__global__ void __launch_bounds__(256) k_agg2(
        const _Float16* __restrict__ h2s, const int* __restrict__ offsets,
        const unsigned short* __restrict__ csr, const float* __restrict__ dinv,
        const float* __restrict__ We, float* __restrict__ Ppart) {
    int b = blockIdx.x;
    int slice = (b & 7) >> 1;
    int grp = (b >> 3) * 2 + (b & 1);
    int t = threadIdx.x;
    int l = t & 63, w = t >> 6;
    int n = grp * 4 + w;
    int eidx = l >> 4, c2 = l & 15;   // edge-in-group, channel-pair
    const __half2* tab = (const __half2*)h2s + (size_t)slice * (NU * 16);
    int s = offsets[n], e = offsets[n + 1];
    float2 acc = make_float2(0.f, 0.f);
    for (int j0 = s; j0 < e; j0 += 8) {
        int j1 = j0 + eidx, j2 = j0 + 4 + eidx;
        if (j1 < e) {
            int r = csr[j1];
            float2 v = __half22float2(tab[r * 16 + c2]);
            acc.x += v.x; acc.y += v.y;
        }
        if (j2 < e) {
            int r = csr[j2];
            float2 v = __half22float2(tab[r * 16 + c2]);
            acc.x += v.x; acc.y += v.y;
        }
    }
    if (eidx == 0) {  // self term (table pre-scaled by dinv[n])
        float2 v = __half22float2(tab[n * 16 + c2]);
        acc.x += v.x; acc.y += v.y;
    }
    // reduce over the 4 edge groups
    acc.x += __shfl_xor(acc.x, 16, 64); acc.y += __shfl_xor(acc.y, 16, 64);
    acc.x += __shfl_xor(acc.x, 32, 64); acc.y += __shfl_xor(acc.y, 32, 64);
    float dn = dinv[n];
    float v0 = fmaxf(acc.x * dn, 0.f);
    float v1 = fmaxf(acc.y * dn, 0.f);
    float p[NC];
#pragma unroll
    for (int q = 0; q < NC; q++) {
        float2 wv = *(const float2*)&We[q * 256 + slice * 32 + 2 * c2];
        p[q] = wv.x * v0 + wv.y * v1;
    }
    // reduce over the 16 channel-pairs
#pragma unroll
    for (int q = 0; q < NC; q++) {
#pragma unroll
        for (int d = 8; d >= 1; d >>= 1) p[q] += __shfl_xor(p[q], d, 64);
    }
    if (l == 0) {
        float2* dst = (float2*)&Ppart[((size_t)slice * NU + n) * NC];
#pragma unroll
        for (int q = 0; q < 5; q++) dst[q] = make_float2(p[2 * q], p[2 * q + 1]);
    }
}

// sum the 4 slice partials into P (user rows)
__global__ void k_psum(const float* __restrict__ Ppart, float* __restrict__ P) {
    int i = blockIdx.x * 256 + threadIdx.x;
    if (i < NU * NC) {
        P[i] = Ppart[i] + Ppart[NU * NC + i] + Ppart[2 * NU * NC + i] + Ppart[3 * NU * NC + i];
    }
}

// ============ movie projection from relu'd fp16: P_m = We_m . h2m ============
__global__ void k_mproj(const __half2* __restrict__ h2m16, const float* __restrict__ We,
                        float* __restrict__ P) {
    int t = threadIdx.x;
    int l = t & 63, w = t >> 6;
    int n = blockIdx.x * 4 + w;   // movie-local index
    float2 xv = __half22float2(h2m16[n * 64 + l]);
    float p[NC];
#pragma unroll
    for (int q = 0; q < NC; q++) {
        float2 wv = *(const float2*)&We[q * 256 + 128 + 2 * l];
        p[q] = wv.x * xv.x + wv.y * xv.y;
    }
#pragma unroll
    for (int q = 0; q < NC; q++) {
#pragma unroll
        for (int d = 32; d >= 1; d >>= 1) p[q] += __shfl_xor(p[q], d, 64);
    }
    if (l == 0) {
#pragma unroll
        for (int q = 0; q < NC; q++) P[(NU + n) * NC + q] = p[q];
    }
}

// ============ edge output: out[e] = P[row[e]] + P[NU + col[e]] + be ============
__global__ void k_edge_out(const int* __restrict__ row, const int* __restrict__ col,
                           const float* __restrict__ P, const float* __restrict__ be,
                           float* __restrict__ out, int E) {
    __shared__ float ls[256 * 11];
    int t = threadIdx.x;
    int e0 = blockIdx.x * 256;
    int e = e0 + t;
    if (e < E) {
        int r = row[e], c = col[e];
        const float2* pu = (const float2*)(P + (size_t)r * NC);
        const float2* pm = (const float2*)(P + (size_t)(NU + c) * NC);
        const float2* be2 = (const float2*)be;
#pragma unroll
        for (int q = 0; q < 5; q++) {
            float2 a = pu[q], b = pm[q], bb = be2[q];
            ls[t * 11 + 2 * q] = a.x + b.x + bb.x;
            ls[t * 11 + 2 * q + 1] = a.y + b.y + bb.y;
        }
    }
    __syncthreads();
    int nvals = (E - e0 < 256 ? E - e0 : 256) * NC;
    size_t base = (size_t)e0 * NC;
    for (int k = t; k < nvals; k += 256) {
        int ee = k / NC, q = k - ee * NC;
        out[base + k] = ls[ee * 11 + q];
    }
}

extern "C" void kernel_launch(void* const* d_in, const int* in_sizes, int n_in,
                              void* d_out, int out_size, void* d_ws, size_t ws_size,
                              hipStream_t stream) {
    const float* x_user  = (const float*)d_in[0];
    const float* x_movie = (const float*)d_in[1];
    const int*   ei      = (const int*)d_in[2];
    const float* Wu = (const float*)d_in[3];
    const float* bu = (const float*)d_in[4];
    const float* Wm = (const float*)d_in[5];
    const float* bm = (const float*)d_in[6];
    const float* W1 = (const float*)d_in[7];
    const float* b1 = (const float*)d_in[8];
    const float* W2 = (const float*)d_in[9];
    const float* b2 = (const float*)d_in[10];
    const float* We = (const float*)d_in[11];
    const float* be = (const float*)d_in[12];
    float* out = (float*)d_out;

    int E = in_sizes[2] / 2;
    const int* row = ei;
    const int* col = ei + E;

    char* p = (char*)d_ws;
    auto alloc = [&](size_t bytes) -> void* {
        void* r = (void*)p;
        p += (bytes + 255) & ~(size_t)255;
        return r;
    };
    int*            counts     = (int*)alloc((size_t)NU * 4);
    int*            offsets    = (int*)alloc((size_t)(NU + 1) * 4);
    unsigned short* csr16      = (unsigned short*)alloc((size_t)E * 2);
    unsigned int*   pairs      = (unsigned int*)alloc((size_t)NB * CAP * 4);
    int*            bucket_cur = (int*)alloc((size_t)NB * 4);
    float*          dinv       = (float*)alloc((size_t)NU * 4);
    float*          beta       = (float*)alloc((size_t)NU * 4);
    int*            sums       = (int*)alloc((size_t)256 * 4);
    float*          WcUT       = (float*)alloc((size_t)FU * HD * 4);
    float*          WcMT       = (float*)alloc((size_t)FM * HD * 4);
    float*          W2T        = (float*)alloc((size_t)HD * HD * 4);
    float*          bcU        = (float*)alloc((size_t)HD * 4);
    float*          bcM        = (float*)alloc((size_t)HD * 4);
    _Float16*       fragWcU    = (_Float16*)alloc((size_t)4096 * 2);
    _Float16*       fragWcM    = (_Float16*)alloc((size_t)8192 * 2);
    _Float16*       fragW2     = (_Float16*)alloc((size_t)16384 * 2);
    __half2*        xs16       = (__half2*)alloc((size_t)NU * FU * 2);
    float*          gfull      = (float*)alloc((size_t)NU * FU * 4);
    _Float16*       h2s        = (_Float16*)alloc((size_t)NU * HD * 2);   // [4][NU][32]
    _Float16*       h2m16      = (_Float16*)alloc((size_t)NM * HD * 2);
    float*          Ppart      = (float*)alloc((size_t)4 * NU * NC * 4);  // [4][NU][10]
    float*          P          = (float*)alloc((size_t)NN * NC * 4);

    const int tb = 256;
    const int nscan = (NU + 255) / 256;  // 196

    hipMemsetAsync(bucket_cur, 0, (size_t)NB * 4, stream);
    k_bucket<<<(E + CHUNK - 1) / CHUNK, 256, 0, stream>>>(row, col, E, bucket_cur, pairs);
    k_bcount<<<NB, 256, 0, stream>>>(pairs, bucket_cur, counts);
    k_scanA<<<nscan, 256, 0, stream>>>(counts, sums);
    k_scanB<<<1, 256, 0, stream>>>(sums, nscan, offsets);
    k_scanC<<<nscan, 256, 0, stream>>>(counts, sums, offsets, dinv);
    k_scatter<<<NB, 256, 0, stream>>>(pairs, bucket_cur, offsets, csr16);

    k_fold<<<113, 256, 0, stream>>>(Wu, bu, Wm, bm, W1, b1, W2, WcUT, bcU, WcMT, bcM, W2T);
    k_wfrag<<<14, 256, 0, stream>>>(WcUT, WcMT, W2T, fragWcU, fragWcM, fragW2);
    k_half<<<(NU * FU / 2 + 255) / 256, 256, 0, stream>>>(x_user, dinv, xs16, NU * FU / 2);

    k_agg1<<<NU / 4, 256, 0, stream>>>(xs16, x_user, offsets, csr16, dinv, gfull, beta);

    k_user<<<(NU + 63) / 64, 256, 0, stream>>>(gfull, beta, fragWcU, bcU, fragW2, b2, dinv, h2s);
    k_movie<<<(NM + 63) / 64, 256, 0, stream>>>(x_movie, fragWcM, bcM, fragW2, b2, h2m16);

    // 8 * 6250 blocks: slice = (b&7)>>1 pins each slice to 2 XCDs; no atomics
    k_agg2<<<50000, 256, 0, stream>>>(h2s, offsets, csr16, dinv, We, Ppart);
    k_psum<<<(NU * NC + 255) / 256, 256, 0, stream>>>(Ppart, P);
    k_mproj<<<NM / 4, 256, 0, stream>>>((const __half2*)h2m16, We, P);

    k_edge_out<<<(E + tb - 1) / tb, tb, 0, stream>>>(row, col, P, be, out, E);
}